// Round 4
// baseline (1404.784 us; speedup 1.0000x reference)
//
#include <hip/hip_runtime.h>

typedef __bf16 bf16x8 __attribute__((ext_vector_type(8)));
typedef float  f32x4  __attribute__((ext_vector_type(4)));

#define TW     16      // pred tile width (pixels)
#define TH     4       // pred tile height
#define NPX    64      // pixels per pred block
#define HLW    22      // halo width  = TW+6
#define HLH    10      // halo height = TH+6
#define HN     220     // HLW*HLH
#define KK     7
#define NCLASS 49
#define IMW    256
#define IMH    256
#define HW     65536   // 256*256

// ---------------------------------------------------------------------------
// Kernel A: m_mask, written as long contiguous streams.
// One block per (class c, plane chunk, batch b): writes 64 KB contiguous.
// ---------------------------------------------------------------------------
__device__ __forceinline__ float axw(float a, float fc) {
    // weight of integer cell fc for coordinate a (= motion + 3), bilinear
    float f  = floorf(a);
    float fr = a - f;
    return (f == fc) ? (1.0f - fr) : ((f == fc - 1.0f) ? fr : 0.0f);
}

__global__ __launch_bounds__(256, 8)
void mask_kernel(const float* __restrict__ gt_motion,
                 float* __restrict__ out_mask)
{
    const int c     = blockIdx.x;   // 0..48
    const int chunk = blockIdx.y;   // 0..3
    const int b     = blockIdx.z;   // 0..15
    const float fcy = (float)(c / KK);
    const float fcx = (float)(c % KK);

    const float* mx = gt_motion + (size_t)b * 2 * HW;   // channel 0 -> x
    const float* my = mx + HW;                          // channel 1 -> y
    float* dst = out_mask + ((size_t)b * NCLASS + c) * HW;

    const int base = chunk * 16384;
    #pragma unroll 4
    for (int it = 0; it < 16; it++) {
        int px = base + it * 1024 + threadIdx.x * 4;
        float4 vx = *reinterpret_cast<const float4*>(mx + px);
        float4 vy = *reinterpret_cast<const float4*>(my + px);
        float4 o;
        o.x = axw(vy.x + 3.0f, fcy) * axw(vx.x + 3.0f, fcx);
        o.y = axw(vy.y + 3.0f, fcy) * axw(vx.y + 3.0f, fcx);
        o.z = axw(vy.z + 3.0f, fcy) * axw(vx.z + 3.0f, fcx);
        o.w = axw(vy.w + 3.0f, fcy) * axw(vx.w + 3.0f, fcx);
        *reinterpret_cast<float4*>(dst + px) = o;
    }
}

// ---------------------------------------------------------------------------
// Kernel B: pred (round-3 structure, mask stores removed)
// ---------------------------------------------------------------------------
__global__ __launch_bounds__(256, 4)
void pred_kernel(const float* __restrict__ im_input,
                 const float* __restrict__ gt_motion,
                 const float* __restrict__ m_kernel,
                 float* __restrict__ out_pred)
{
    __shared__ float  omW[NCLASS * NPX];                 // om[n*64+px] then W[px*49+t]
    __shared__ float  Klds[NCLASS * NCLASS];             // f32 K for the scatter
    __shared__ __align__(16) __bf16 KT[64 * 64];         // B-operand K^T, zero-padded
    __shared__ float2 halo[HN];                          // motion (ay,ax); sentinel -8
    __shared__ float  iml[3 * HN];                       // im halo
    __shared__ float  pr_red[4 * 3 * NPX];               // cross-wave pred partials

    const int tid  = threadIdx.x;
    const int wv   = tid >> 6, lane = tid & 63;
    const int lx   = lane & 15, ly = lane >> 4;
    const int x0 = blockIdx.x * TW, y0 = blockIdx.y * TH;
    const int b  = blockIdx.z;

    // ---- staging ----
    for (int i = tid; i < NCLASS * NCLASS; i += 256) Klds[i] = m_kernel[i];

    for (int i = tid; i < 64 * 64; i += 256) {
        int t = i >> 6, k = i & 63;
        KT[i] = (__bf16)((t < NCLASS && k < NCLASS) ? m_kernel[k * NCLASS + t] : 0.0f);
    }

    const float* mot_x = gt_motion + (size_t)b * 2 * HW;
    const float* mot_y = mot_x + HW;
    for (int i = tid; i < HN; i += 256) {
        int hy = i / HLW, hx = i - hy * HLW;
        int gy = y0 - 3 + hy, gx = x0 - 3 + hx;
        float2 v;
        if (gy >= 0 && gy < IMH && gx >= 0 && gx < IMW) {
            int off = gy * IMW + gx;
            v.x = mot_y[off] + 3.0f;
            v.y = mot_x[off] + 3.0f;
        } else {
            v.x = -8.0f; v.y = -8.0f;
        }
        halo[i] = v;
    }

    const float* imP = im_input + ((size_t)b * 6 + 3) * HW;
    for (int i = tid; i < 3 * HN; i += 256) {
        int c  = i / HN, r = i - c * HN;
        int hy = r / HLW, hx = r - hy * HLW;
        int gy = y0 - 3 + hy, gx = x0 - 3 + hx;
        float v = 0.0f;
        if (gy >= 0 && gy < IMH && gx >= 0 && gx < IMW)
            v = imP[c * HW + gy * IMW + gx];
        iml[i] = v;
    }

    for (int i = tid; i < NCLASS * NPX; i += 256) omW[i] = 0.0f;

    __syncthreads();

    // ---- om scatter (neighbors split across waves) ----
    #pragma unroll
    for (int s = 0; s < NCLASS; s++) {
        if ((s & 3) != wv) continue;       // wave-uniform, s compile-time
        const int u = s / KK, v2 = s % KK;
        float2 h = halo[(ly + u) * HLW + (lx + v2)];
        float ayc = h.x, axc = h.y;
        float iyf = floorf(ayc), ixf = floorf(axc);
        float fy = ayc - iyf,    fx = axc - ixf;
        bool  valid = (ayc >= 0.0f);
        float wy0 = valid ? (1.0f - fy) : 0.0f;
        float wy1 = valid ? fy : 0.0f;
        int   n00 = valid ? ((int)iyf * KK + (int)ixf) : 0;
        const float* kb = &Klds[n00 * NCLASS + s];
        float k00 = kb[0];
        float k01 = kb[NCLASS];
        float k10 = kb[KK * NCLASS];
        float k11 = kb[(KK + 1) * NCLASS];
        float wx0 = 1.0f - fx;
        float* ob = &omW[n00 * NPX + lane];
        atomicAdd(ob,           wy0 * wx0 * k00);
        atomicAdd(ob + NPX,     wy0 * fx  * k01);
        atomicAdd(ob + 7 * NPX, wy1 * wx0 * k10);
        atomicAdd(ob + 8 * NPX, wy1 * fx  * k11);
    }

    __syncthreads();   // om complete

    // ---- MFMA fragments (wave wv owns pixel slab wv*16 .. wv*16+15) ----
    const int mpx  = wv * 16 + (lane & 15);
    const int krow = (lane >> 4) * 8;
    bf16x8 af[2];
    #pragma unroll
    for (int kit = 0; kit < 2; kit++) {
        int k0 = kit * 32 + krow;
        bf16x8 a;
        #pragma unroll
        for (int j = 0; j < 8; j++) {
            int n  = k0 + j;
            int nn = (n < NCLASS) ? n : (NCLASS - 1);
            float v = omW[nn * NPX + mpx];
            a[j] = (__bf16)((n < NCLASS) ? v : 0.0f);
        }
        af[kit] = a;
    }
    bf16x8 bfr[2][4];
    #pragma unroll
    for (int kit = 0; kit < 2; kit++) {
        #pragma unroll
        for (int nt = 0; nt < 4; nt++) {
            int t  = nt * 16 + (lane & 15);
            int k0 = kit * 32 + krow;
            bfr[kit][nt] = *reinterpret_cast<const bf16x8*>(&KT[t * 64 + k0]);
        }
    }

    __syncthreads();   // all om reads done before W overwrites the buffer

    // ---- W[64x49] = om[64x64] x K^T[64x49pad] via MFMA ----
    f32x4 acc[4];
    #pragma unroll
    for (int nt = 0; nt < 4; nt++) {
        f32x4 c = {0.0f, 0.0f, 0.0f, 0.0f};
        c = __builtin_amdgcn_mfma_f32_16x16x32_bf16(af[0], bfr[0][nt], c, 0, 0, 0);
        c = __builtin_amdgcn_mfma_f32_16x16x32_bf16(af[1], bfr[1][nt], c, 0, 0, 0);
        acc[nt] = c;
    }
    #pragma unroll
    for (int nt = 0; nt < 4; nt++) {
        int t = nt * 16 + (lane & 15);
        if (t < NCLASS) {
            #pragma unroll
            for (int r = 0; r < 4; r++) {
                int px = wv * 16 + (lane >> 4) * 4 + r;
                omW[px * NCLASS + t] = acc[nt][r];
            }
        }
    }

    __syncthreads();   // W ready

    // ---- apply effective 7x7 (taps split across waves) ----
    float a0 = 0.0f, a1 = 0.0f, a2 = 0.0f;
    #pragma unroll
    for (int t = 0; t < NCLASS; t++) {
        if ((t & 3) != wv) continue;       // wave-uniform
        const int p = t / KK, q = t % KK;
        float wvv = omW[lane * NCLASS + t];
        int   hi = (ly + p) * HLW + (lx + q);
        a0 = fmaf(wvv, iml[hi],          a0);
        a1 = fmaf(wvv, iml[hi + HN],     a1);
        a2 = fmaf(wvv, iml[hi + 2 * HN], a2);
    }
    pr_red[wv * 192 + 0 * NPX + lane] = a0;
    pr_red[wv * 192 + 1 * NPX + lane] = a1;
    pr_red[wv * 192 + 2 * NPX + lane] = a2;

    __syncthreads();

    if (tid < 3 * NPX) {
        float v = pr_red[tid] + pr_red[192 + tid] + pr_red[384 + tid] + pr_red[576 + tid];
        int c = tid >> 6, px = tid & 63;
        out_pred[(size_t)b * 3 * HW + (size_t)c * HW +
                 (y0 + (px >> 4)) * IMW + (x0 + (px & 15))] = v;
    }
}

extern "C" void kernel_launch(void* const* d_in, const int* in_sizes, int n_in,
                              void* d_out, int out_size, void* d_ws, size_t ws_size,
                              hipStream_t stream) {
    const float* im_input  = (const float*)d_in[0];
    // d_in[1] = im_output: unused by the reference computation
    const float* gt_motion = (const float*)d_in[2];
    const float* m_kernel  = (const float*)d_in[3];

    float* pred = (float*)d_out;                        // (16,3,256,256)
    float* mask = pred + (size_t)16 * 3 * HW;           // (16,49,256,256)

    {   // mask: contiguous streaming writes
        dim3 grid(NCLASS, 4, 16);
        dim3 block(256);
        hipLaunchKernelGGL(mask_kernel, grid, block, 0, stream, gt_motion, mask);
    }
    {   // pred
        dim3 grid(IMW / TW, IMH / TH, 16);
        dim3 block(256);
        hipLaunchKernelGGL(pred_kernel, grid, block, 0, stream,
                           im_input, gt_motion, m_kernel, pred);
    }
}

// Round 5
// 353.959 us; speedup vs baseline: 3.9688x; 3.9688x over previous
//
#include <hip/hip_runtime.h>

typedef __bf16 bf16x8 __attribute__((ext_vector_type(8)));
typedef float  f32x4  __attribute__((ext_vector_type(4)));

#define TILE   16
#define HALO   22      // TILE + 6
#define KK     7
#define NCLASS 49
#define IMW    256
#define IMH    256
#define HW     65536   // 256*256
#define HH     484     // HALO*HALO

__global__ __launch_bounds__(256, 2)
void gtnet_kernel(const float* __restrict__ im_input,
                  const float* __restrict__ gt_motion,
                  const float* __restrict__ m_kernel,
                  float* __restrict__ out_pred,
                  float* __restrict__ out_mask)
{
    // omW: om accumulator (class-major om[n*256+px], thread-private columns ->
    // plain read-modify-write, NO atomics), then reused as W (pixel-major W[px*49+t]).
    __shared__ float  omW[NCLASS * 256];              // 50176 B
    __shared__ float2 halo[HH];                       // 3872 B (motion ay,ax; sentinel -8)
    __shared__ float  KS[NCLASS * NCLASS];            // 9604 B  KS[s][n] = K[n][s] (transposed)
    __shared__ __align__(16) __bf16 KT[64 * 72];      // 9216 B (B-operand K^T, zero-padded)
    __shared__ float  iml[3 * HH];                    // 5808 B (im halo)
    // total 78676 B -> 2 blocks/CU

    const int tid  = threadIdx.x;
    const int lane = tid & 63, wv_id = tid >> 6;
    const int tx = tid & 15, ty = tid >> 4;
    const int x0 = blockIdx.x * TILE, y0 = blockIdx.y * TILE;
    const int b  = blockIdx.z;
    const int x = x0 + tx, y = y0 + ty;

    // ---------------- phase 1: staging ----------------
    // KS[s][n] = m_kernel[n][s]  (transposed so the 4-gather is 2 adjacent pairs)
    for (int i = tid; i < NCLASS * NCLASS; i += 256) {
        int s = i / NCLASS, n = i - s * NCLASS;
        KS[i] = m_kernel[n * NCLASS + s];
    }

    for (int i = tid; i < 64 * 72; i += 256) {
        int t = i / 72, n = i - t * 72;
        float v = (t < NCLASS && n < NCLASS) ? m_kernel[n * NCLASS + t] : 0.0f;
        KT[i] = (__bf16)v;
    }

    const float* mot_x = gt_motion + (size_t)b * 2 * HW;  // channel 0 -> ax
    const float* mot_y = mot_x + HW;                      // channel 1 -> ay
    for (int i = tid; i < HH; i += 256) {
        int hy = i / HALO, hx = i - hy * HALO;
        int gy = y0 - 3 + hy, gx = x0 - 3 + hx;
        float2 v;
        if (gy >= 0 && gy < IMH && gx >= 0 && gx < IMW) {
            int off = gy * IMW + gx;
            v.x = mot_y[off] + 3.0f;
            v.y = mot_x[off] + 3.0f;
        } else {
            v.x = -8.0f; v.y = -8.0f;
        }
        halo[i] = v;
    }

    #pragma unroll
    for (int n = 0; n < NCLASS; n++) omW[n * 256 + tid] = 0.0f;

    // issue im halo global loads early (consumed before the om barrier)
    const float* imP = im_input + ((size_t)b * 6 + 3) * HW;  // last 3 channels
    float imreg[6];
    #pragma unroll
    for (int k2 = 0; k2 < 6; k2++) {
        int i = tid + k2 * 256;
        float val = 0.0f;
        if (i < 3 * HH) {
            int c  = i / HH;
            int r  = i - c * HH;
            int hy = r / HALO, hx = r - hy * HALO;
            int gy = y0 - 3 + hy, gx = x0 - 3 + hx;
            if (gy >= 0 && gy < IMH && gx >= 0 && gx < IMW)
                val = imP[c * HW + gy * IMW + gx];
        }
        imreg[k2] = val;
    }

    __syncthreads();

    // ---------------- phase 2: m_mask dense write ----------------
    {
        float2 h = halo[(ty + 3) * HALO + (tx + 3)];
        float iyf = floorf(h.x), ixf = floorf(h.y);
        float fy = h.x - iyf,    fx = h.y - ixf;
        int   iy = (int)iyf,     ix = (int)ixf;
        float wyA[KK], wxB[KK];
        #pragma unroll
        for (int a = 0; a < KK; a++) {
            wyA[a] = (a == iy) ? (1.0f - fy) : ((a == iy + 1) ? fy : 0.0f);
            wxB[a] = (a == ix) ? (1.0f - fx) : ((a == ix + 1) ? fx : 0.0f);
        }
        float* mm = out_mask + (size_t)b * NCLASS * HW + y * IMW + x;
        #pragma unroll
        for (int a = 0; a < KK; a++)
            #pragma unroll
            for (int bb = 0; bb < KK; bb++)
                mm[(size_t)(a * KK + bb) * HW] = wyA[a] * wxB[bb];
    }

    // ---------------- phase 3: om scatter, plain RMW (columns are thread-private) ----
    #pragma unroll
    for (int u = 0; u < KK; u++) {
        #pragma unroll
        for (int v = 0; v < KK; v++) {
            const int s = u * KK + v;                  // compile-time
            float2 h = halo[(ty + u) * HALO + (tx + v)];
            float ayc = h.x, axc = h.y;
            float iyf = floorf(ayc), ixf = floorf(axc);
            float fy = ayc - iyf,    fx = axc - ixf;
            bool  valid = (ayc >= 0.0f);
            float wy0 = valid ? (1.0f - fy) : 0.0f;
            float wy1 = valid ? fy : 0.0f;
            int   n00 = valid ? ((int)iyf * KK + (int)ixf) : 0;
            const float* kb = &KS[s * NCLASS + n00];   // 4 adjacent-ish taps
            float k00 = kb[0];
            float k01 = kb[1];
            float k10 = kb[KK];
            float k11 = kb[KK + 1];
            float wx0 = 1.0f - fx;
            float* ob = &omW[n00 * 256 + tid];
            ob[0]       += wy0 * wx0 * k00;
            ob[256]     += wy0 * fx  * k01;
            ob[7 * 256] += wy1 * wx0 * k10;
            ob[8 * 256] += wy1 * fx  * k11;
        }
    }

    // stage im halo into its LDS region (read much later, after barrier)
    #pragma unroll
    for (int k2 = 0; k2 < 6; k2++) {
        int i = tid + k2 * 256;
        if (i < 3 * HH) iml[i] = imreg[k2];
    }

    __syncthreads();   // om complete

    // ---------------- phase 4: load MFMA fragments ----------------
    bf16x8 af[2][4];   // [kiter][mtile]
    #pragma unroll
    for (int kit = 0; kit < 2; kit++) {
        #pragma unroll
        for (int mt = 0; mt < 4; mt++) {
            int px = wv_id * 64 + mt * 16 + (lane & 15);
            int k0 = kit * 32 + (lane >> 4) * 8;
            bf16x8 a;
            #pragma unroll
            for (int j = 0; j < 8; j++) {
                int n  = k0 + j;
                int nn = (n < NCLASS) ? n : (NCLASS - 1);
                float v = omW[nn * 256 + px];
                a[j] = (__bf16)((n < NCLASS) ? v : 0.0f);
            }
            af[kit][mt] = a;
        }
    }
    bf16x8 bfr[2][4];  // [kiter][ntile]
    #pragma unroll
    for (int kit = 0; kit < 2; kit++) {
        #pragma unroll
        for (int nt = 0; nt < 4; nt++) {
            int t  = nt * 16 + (lane & 15);
            int k0 = kit * 32 + (lane >> 4) * 8;
            bfr[kit][nt] = *reinterpret_cast<const bf16x8*>(&KT[t * 72 + k0]);
        }
    }

    __syncthreads();   // all om reads done before W overwrites the region

    // ---------------- phase 5: MFMA GEMM  W[256x49] = om[256x64] x K^T[64x49pad] ----
    f32x4 acc[4][4];
    #pragma unroll
    for (int mt = 0; mt < 4; mt++) {
        #pragma unroll
        for (int nt = 0; nt < 4; nt++) {
            f32x4 c = {0.0f, 0.0f, 0.0f, 0.0f};
            c = __builtin_amdgcn_mfma_f32_16x16x32_bf16(af[0][mt], bfr[0][nt], c, 0, 0, 0);
            c = __builtin_amdgcn_mfma_f32_16x16x32_bf16(af[1][mt], bfr[1][nt], c, 0, 0, 0);
            acc[mt][nt] = c;
        }
    }

    // writeback: C/D layout col=lane&15 (t), row=(lane>>4)*4+reg (px) -> W[px*49+t]
    #pragma unroll
    for (int mt = 0; mt < 4; mt++) {
        #pragma unroll
        for (int nt = 0; nt < 4; nt++) {
            int t = nt * 16 + (lane & 15);
            if (t < NCLASS) {
                #pragma unroll
                for (int r = 0; r < 4; r++) {
                    int px = wv_id * 64 + mt * 16 + (lane >> 4) * 4 + r;
                    omW[px * NCLASS + t] = acc[mt][nt][r];
                }
            }
        }
    }

    __syncthreads();   // W complete

    // ---------------- phase 6: apply effective 7x7 kernel ----------------
    float wv[NCLASS];
    #pragma unroll
    for (int t = 0; t < NCLASS; t++) wv[t] = omW[tid * NCLASS + t];

    float a0 = 0.0f, a1 = 0.0f, a2 = 0.0f;
    #pragma unroll
    for (int p = 0; p < KK; p++) {
        #pragma unroll
        for (int q = 0; q < KK; q++) {
            float wvv = wv[p * KK + q];
            int   hi = (ty + p) * HALO + (tx + q);
            a0 = fmaf(wvv, iml[hi],          a0);
            a1 = fmaf(wvv, iml[hi + HH],     a1);
            a2 = fmaf(wvv, iml[hi + 2 * HH], a2);
        }
    }
    float* pr = out_pred + (size_t)b * 3 * HW + y * IMW + x;
    pr[0]      = a0;
    pr[HW]     = a1;
    pr[2 * HW] = a2;
}

extern "C" void kernel_launch(void* const* d_in, const int* in_sizes, int n_in,
                              void* d_out, int out_size, void* d_ws, size_t ws_size,
                              hipStream_t stream) {
    const float* im_input  = (const float*)d_in[0];
    // d_in[1] = im_output: unused by the reference computation
    const float* gt_motion = (const float*)d_in[2];
    const float* m_kernel  = (const float*)d_in[3];

    float* pred = (float*)d_out;                        // (16,3,256,256)
    float* mask = pred + (size_t)16 * 3 * HW;           // (16,49,256,256)

    dim3 grid(IMW / TILE, IMH / TILE, 16);
    dim3 block(256);
    hipLaunchKernelGGL(gtnet_kernel, grid, block, 0, stream,
                       im_input, gt_motion, m_kernel, pred, mask);
}